// Round 1
// baseline (48.855 us; speedup 1.0000x reference)
//
#include <hip/hip_runtime.h>
#include <math.h>

// Problem: B=32, S=4096, Hd=256.
// scores[b,s] = dot(u[b,s,:], wu_eff) + c[b], with wu_eff[h] = sum_k v_param[k]*W_attn[k,h].
// c[b] (from v@Wv.T + b_attn) is constant over s -> cancels in softmax -> never computed.
// attn = softmax_s(scores); w_d[b] = sum_s ||u[b,s]-v[b]|| * attn[b,s].
// Memory-bound: single fused pass over u (134 MB).

#define S_LEN 4096
#define HD    256
#define B_N   32

__global__ void wu_eff_kernel(const float* __restrict__ W, const float* __restrict__ vp,
                              float* __restrict__ wu) {
    const int h = threadIdx.x;                 // 256 threads, coalesced over h
    float acc = 0.f;
#pragma unroll 8
    for (int k = 0; k < HD; ++k)
        acc = fmaf(vp[k], W[k * (2 * HD) + h], acc);   // Wu[k,h] = W_attn[k,h]
    wu[h] = acc;
}

// One 64-lane wave per (b,s) row; 4 rows per 256-thread block.
__global__ void score_dist_kernel(const float* __restrict__ u, const float* __restrict__ v,
                                  const float* __restrict__ wu,
                                  float* __restrict__ scores, float* __restrict__ dist) {
    const int b    = blockIdx.y;
    const int wave = threadIdx.x >> 6;
    const int lane = threadIdx.x & 63;
    const int s    = (blockIdx.x << 2) + wave;

    __shared__ float s_wu[HD];
    __shared__ float s_v[HD];
    if (threadIdx.x < HD) {
        s_wu[threadIdx.x] = wu[threadIdx.x];
        s_v[threadIdx.x]  = v[b * HD + threadIdx.x];
    }
    __syncthreads();

    const size_t row = ((size_t)b * S_LEN + s) * HD;
    const float4 u4 = *reinterpret_cast<const float4*>(u + row + lane * 4);
    const float4 w4 = *reinterpret_cast<const float4*>(&s_wu[lane * 4]);
    const float4 v4 = *reinterpret_cast<const float4*>(&s_v[lane * 4]);

    float sc = u4.x * w4.x + u4.y * w4.y + u4.z * w4.z + u4.w * w4.w;
    const float dx = u4.x - v4.x, dy = u4.y - v4.y, dz = u4.z - v4.z, dw = u4.w - v4.w;
    float dd = dx * dx + dy * dy + dz * dz + dw * dw;

#pragma unroll
    for (int off = 32; off > 0; off >>= 1) {
        sc += __shfl_down(sc, off);
        dd += __shfl_down(dd, off);
    }
    if (lane == 0) {
        scores[b * S_LEN + s] = sc;
        dist[b * S_LEN + s]   = sqrtf(dd);
    }
}

// One block per batch row b: softmax over S=4096 + weighted distance sum.
__global__ void softmax_wd_kernel(const float* __restrict__ scores, const float* __restrict__ dist,
                                  float* __restrict__ w_d, float* __restrict__ attn) {
    const int b    = blockIdx.x;
    const int t    = threadIdx.x;          // 1024 threads, 4 elems each
    const int wave = t >> 6;
    const int lane = t & 63;

    __shared__ float red[16];
    __shared__ float red2[16];

    float sc[4], ds[4];
#pragma unroll
    for (int i = 0; i < 4; ++i) {
        const int s = t + i * 1024;
        sc[i] = scores[b * S_LEN + s];
        ds[i] = dist[b * S_LEN + s];
    }

    // block-max
    float m = fmaxf(fmaxf(sc[0], sc[1]), fmaxf(sc[2], sc[3]));
#pragma unroll
    for (int off = 32; off > 0; off >>= 1) m = fmaxf(m, __shfl_down(m, off));
    if (lane == 0) red[wave] = m;
    __syncthreads();
    if (t < 64) {
        float y = (lane < 16) ? red[lane] : -INFINITY;
#pragma unroll
        for (int off = 8; off > 0; off >>= 1) y = fmaxf(y, __shfl_down(y, off));
        if (lane == 0) red[0] = y;
    }
    __syncthreads();
    const float M = red[0];
    __syncthreads();

    float e[4];
    float sum = 0.f, sde = 0.f;
#pragma unroll
    for (int i = 0; i < 4; ++i) {
        e[i] = expf(sc[i] - M);
        sum += e[i];
        sde += e[i] * ds[i];
    }
#pragma unroll
    for (int off = 32; off > 0; off >>= 1) {
        sum += __shfl_down(sum, off);
        sde += __shfl_down(sde, off);
    }
    if (lane == 0) { red[wave] = sum; red2[wave] = sde; }
    __syncthreads();
    if (t < 64) {
        float a = (lane < 16) ? red[lane] : 0.f;
        float c = (lane < 16) ? red2[lane] : 0.f;
#pragma unroll
        for (int off = 8; off > 0; off >>= 1) {
            a += __shfl_down(a, off);
            c += __shfl_down(c, off);
        }
        if (lane == 0) { red[0] = a; red2[0] = c; }
    }
    __syncthreads();
    const float inv = 1.f / red[0];
    if (t == 0) w_d[b] = red2[0] * inv;
#pragma unroll
    for (int i = 0; i < 4; ++i)
        attn[(size_t)b * S_LEN + t + i * 1024] = e[i] * inv;
}

extern "C" void kernel_launch(void* const* d_in, const int* in_sizes, int n_in,
                              void* d_out, int out_size, void* d_ws, size_t ws_size,
                              hipStream_t stream) {
    const float* u  = (const float*)d_in[0];   // (32, 4096, 256)
    const float* v  = (const float*)d_in[1];   // (32, 256)
    const float* W  = (const float*)d_in[2];   // (256, 512)
    // d_in[3] = b_attn: constant over s -> cancels in softmax, unused.
    const float* vp = (const float*)d_in[4];   // (256,)

    float* out  = (float*)d_out;
    float* w_d  = out;          // 32 floats
    float* attn = out + B_N;    // 32*4096 floats

    char*  ws     = (char*)d_ws;
    float* wu     = (float*)ws;                                   // 256 f32
    float* scores = (float*)(ws + 4096);                          // B*S f32
    float* dist   = (float*)(ws + 4096 + (size_t)B_N * S_LEN * 4);// B*S f32

    wu_eff_kernel<<<1, HD, 0, stream>>>(W, vp, wu);
    score_dist_kernel<<<dim3(S_LEN / 4, B_N), 256, 0, stream>>>(u, v, wu, scores, dist);
    softmax_wd_kernel<<<B_N, 1024, 0, stream>>>(scores, dist, w_d, attn);
}